// Round 6
// baseline (384.500 us; speedup 1.0000x reference)
//
#include <hip/hip_runtime.h>

// ---------------------------------------------------------------- constants
#define TTOK 32768
#define DM   256
#define NF   1024
#define KMAX 32

typedef __attribute__((ext_vector_type(8))) unsigned short ushort8;
typedef __attribute__((ext_vector_type(8))) __bf16 bf16x8;
typedef __attribute__((ext_vector_type(4))) float floatx4;

// workspace offsets (all 256B aligned)
constexpr size_t O_SLOT = 0;                                   // 1 uint (max|Wt|)
constexpr size_t O_S    = 256;                                 // 1024 f32 sigmoid(alpha)
constexpr size_t O_WCT  = O_S    + 4096;                       // Wc^T  [1024][256] bf16
constexpr size_t O_WGT  = O_WCT  + (size_t)NF*DM*2;            // Wg^T  [1024][256] bf16
constexpr size_t O_WDT  = O_WGT  + (size_t)NF*DM*2;            // Wd^T  [256][1024] bf16
constexpr size_t O_WTT  = O_WDT  + (size_t)DM*NF*2;            // Wt^T  [256][1024] f32
constexpr size_t O_XBF  = O_WTT  + (size_t)DM*NF*4;            // x bf16 [T][256]
constexpr size_t O_CNT  = O_XBF  + (size_t)TTOK*DM*2;          // counts [T]
constexpr size_t O_CIDX = O_CNT  + (size_t)TTOK*4;             // cand d (raw) [T][KMAX]
constexpr size_t O_CVAL = O_CIDX + (size_t)TTOK*KMAX*4;        // cand val [T][KMAX]
constexpr size_t O_FUSD = O_CVAL + (size_t)TTOK*KMAX*4;        // fused bf16 [T][1024]

__device__ __forceinline__ float bf2f(unsigned short u) {
    union { unsigned int i; float f; } c; c.i = ((unsigned int)u) << 16; return c.f;
}
__device__ __forceinline__ unsigned short f2bf(float v) {
    union { float f; unsigned int i; } c; c.f = v;
    unsigned int b = c.i;
    return (unsigned short)((b + 0x7FFFu + ((b >> 16) & 1u)) >> 16);
}
__device__ __forceinline__ float sigm(float z) { return 1.0f / (1.0f + __expf(-z)); }
// tanh-gelu: max |diff| vs exact erf-gelu ~3e-3, far under 0.266 tolerance
__device__ __forceinline__ float gelu_f(float x) {
    return x * sigm(1.59576912f * (x + 0.044715f * x * x * x));
}
// async global->LDS, 16B per lane; lds dest = wave-uniform base + lane*16 [m97/m104]
__device__ __forceinline__ void g2lds16(const unsigned short* g, unsigned short* l) {
    __builtin_amdgcn_global_load_lds((const __attribute__((address_space(1))) unsigned int*)g,
                                     (__attribute__((address_space(3))) unsigned int*)l, 16, 0, 0);
}

// ------------------------------------------------- kernel 1: pack weights
__global__ void pack_kernel(const float* __restrict__ Wt, const float* __restrict__ alpha,
                            const float* __restrict__ Wc, const float* __restrict__ Wg,
                            const float* __restrict__ Wd,
                            unsigned short* __restrict__ Wct, unsigned short* __restrict__ Wgt,
                            unsigned short* __restrict__ WdT, float* __restrict__ WtT,
                            float* __restrict__ s, unsigned int* __restrict__ slot) {
    int e = blockIdx.x * 256 + threadIdx.x;
    if (e == 0) *slot = 0u;
    { int f = e >> 8, k = e & 255;           // Wc/Wg are [256][1024]
      Wct[e] = f2bf(Wc[k * NF + f]);
      Wgt[e] = f2bf(Wg[k * NF + f]); }
    { int n = e >> 10, k = e & 1023;         // Wd is [1024][256]
      WdT[e] = f2bf(Wd[k * DM + n]); }
    { int d = e >> 10, f = e & 1023;         // Wt is [1024][256]
      WtT[e] = Wt[f * DM + d]; }
    if (e < NF) s[e] = sigm(alpha[e]);
}

// ------------------------------------------------- kernel 2: max|Wt| reduce
__global__ void minmax_kernel(const float* __restrict__ Wt, unsigned int* __restrict__ slot) {
    int g = blockIdx.x * 256 + threadIdx.x;
    float lm = 0.0f;
    for (int i = g; i < NF * DM; i += 128 * 256) lm = fmaxf(lm, fabsf(Wt[i]));
    #pragma unroll
    for (int o = 32; o > 0; o >>= 1) lm = fmaxf(lm, __shfl_xor(lm, o));
    if ((threadIdx.x & 63) == 0) atomicMax(slot, __float_as_uint(lm)); // |w|>=0: uint order ok
}

// ------------------------------------------------- kernel 3: candidates + x->bf16
__global__ void cand_kernel(const float* __restrict__ x, const unsigned int* __restrict__ slot,
                            unsigned short* __restrict__ xbf, int* __restrict__ counts,
                            int* __restrict__ cidx, float* __restrict__ cval) {
    int i = blockIdx.x, t = threadIdx.x;
    float v = x[i * DM + t];
    xbf[i * DM + t] = f2bf(v);
    float m = v;
    #pragma unroll
    for (int o = 32; o > 0; o >>= 1) m = fmaxf(m, __shfl_xor(m, o));
    __shared__ float wm[4];
    __shared__ int cnt;
    __shared__ int sidx[KMAX];
    __shared__ float sval[KMAX];
    if ((t & 63) == 0) wm[t >> 6] = m;
    if (t == 0) cnt = 0;
    __syncthreads();
    float xmax = fmaxf(fmaxf(wm[0], wm[1]), fmaxf(wm[2], wm[3]));
    float delta = 2.0f * __uint_as_float(*slot);   // >= Wmax - Wmin : exact exclusion bound
    float thr = xmax - delta;
    if (v >= thr) {
        int p = atomicAdd(&cnt, 1);
        if (p < KMAX) { sidx[p] = t; sval[p] = v; }   // raw d index
    }
    __syncthreads();
    int c = cnt;
    if (t == 0) counts[i] = c;
    if (t < (c < KMAX ? c : KMAX)) {
        cidx[i * KMAX + t] = sidx[t];
        cval[i * KMAX + t] = sval[t];
    }
}

// ------------------------------------------------- kernel 4: fused GEMM1
// (x@Wc, x@Wg) MFMA + tropical max-plus + convex/concave + gate blend.
// 128x128 tile, BK=32, 512 thr (8 waves 2Mx4F, wave 64x32 dual-output).
// Grid dim3(8, 256): bf fastest -> the 8 blocks sharing an A-tile / cand-meta
// run concurrently -> L2 reuse (r5 FETCH=141MB from bm-fastest order).
// LDS phase-reuse: staging bufs (24KB) die after K-loop; packed cand meta
// (d:ushort | val:bf16, 4B) overlays them. Output staged per-mi in obuf and
// written as 256B contiguous segments (r5 wrote 32B quad-fragments: 172MB).
#define LDSS 32   // ushorts per LDS row, no pad (wave-uniform-base DMA, m104)
#define KPAD 33
#define OSTR 144  // obuf row stride (ushorts), 16B-aligned rows
__global__ __launch_bounds__(512, 4) void gemm1_kernel(
    const unsigned short* __restrict__ A,   // xbf [T][256]
    const unsigned short* __restrict__ Bct, // [1024][256]
    const unsigned short* __restrict__ Bgt, // [1024][256]
    const float* __restrict__ bc, const float* __restrict__ bg,
    const int* __restrict__ counts, const int* __restrict__ cidx,
    const float* __restrict__ cval, const float* __restrict__ x,
    const float* __restrict__ WtT, const float* __restrict__ bt,
    const float* __restrict__ slx, const float* __restrict__ ofx,
    const float* __restrict__ slc, const float* __restrict__ ofc,
    const float* __restrict__ s, unsigned short* __restrict__ fused) {
    __shared__ __align__(16) char smem[25088 + OSTR * 32 * 2];
    unsigned short* As  = (unsigned short*)smem;            // [0, 8K)
    unsigned short* Bcs = As + 4096;                        // [8K, 16K)
    unsigned short* Bgs = As + 8192;                        // [16K, 24K)
    int* sOV  = (int*)smem;                                 // [0, 16.9K) after K-loop
    int* sCnt = (int*)(smem + 24576);                       // [24K, 24.5K)
    unsigned short* obuf = (unsigned short*)(smem + 25088); // [24.5K, ~34K)
    const int t = threadIdx.x;
    const int bf = blockIdx.x, bm = blockIdx.y;
    const int wave = t >> 6, lane = t & 63;
    const int wm = wave & 1, wn = wave >> 1;
    const int lr = lane & 15, quad = lane >> 4;
    const int srow = wave * 16 + (lane >> 2), scol = (lane & 3) << 3;
    const unsigned short* gA = A   + (size_t)(bm * 128 + srow) * DM + scol;
    const unsigned short* gC = Bct + (size_t)(bf * 128 + srow) * DM + scol;
    const unsigned short* gG = Bgt + (size_t)(bf * 128 + srow) * DM + scol;
    unsigned short* lA = &As[wave * 16 * LDSS];
    unsigned short* lC = &Bcs[wave * 16 * LDSS];
    unsigned short* lG = &Bgs[wave * 16 * LDSS];

    if (t < 128) sCnt[t] = counts[bm * 128 + t];

    floatx4 accc[4][2], accg[4][2];
    #pragma unroll
    for (int i = 0; i < 4; i++)
        #pragma unroll
        for (int j = 0; j < 2; j++) { accc[i][j] = (floatx4)0.0f; accg[i][j] = (floatx4)0.0f; }

    for (int k0 = 0; k0 < DM; k0 += 32) {
        __syncthreads();            // covers sCnt stage (1st iter) + prior ds_reads
        g2lds16(gA + k0, lA);
        g2lds16(gC + k0, lC);
        g2lds16(gG + k0, lG);
        __syncthreads();
        bf16x8 af[4], bcf[2], bgf[2];
        #pragma unroll
        for (int mi = 0; mi < 4; mi++)
            af[mi] = *(const bf16x8*)&As[(wm * 64 + mi * 16 + lr) * LDSS + quad * 8];
        #pragma unroll
        for (int ni = 0; ni < 2; ni++) {
            bcf[ni] = *(const bf16x8*)&Bcs[(wn * 32 + ni * 16 + lr) * LDSS + quad * 8];
            bgf[ni] = *(const bf16x8*)&Bgs[(wn * 32 + ni * 16 + lr) * LDSS + quad * 8];
        }
        #pragma unroll
        for (int mi = 0; mi < 4; mi++)
            #pragma unroll
            for (int ni = 0; ni < 2; ni++) {
                accc[mi][ni] = __builtin_amdgcn_mfma_f32_16x16x32_bf16(af[mi], bcf[ni], accc[mi][ni], 0, 0, 0);
                accg[mi][ni] = __builtin_amdgcn_mfma_f32_16x16x32_bf16(af[mi], bgf[ni], accg[mi][ni], 0, 0, 0);
            }
    }
    __syncthreads();   // staging bufs dead; overlay sOV

    // ---- stage packed candidate meta (pre-padded: d=0, val=-1e30 -> branchless)
    const int PADV = (int)(((unsigned int)f2bf(-1e30f)) << 16);
    for (int e = t; e < 128 * KMAX; e += 512) {
        int m = e >> 5, k = e & 31;
        int c = sCnt[m];
        int pk = PADV;
        if (k < (c < KMAX ? c : KMAX)) {
            int d  = cidx[(size_t)(bm * 128 + m) * KMAX + k];
            float v = cval[(size_t)(bm * 128 + m) * KMAX + k];
            pk = (int)(((unsigned int)f2bf(v)) << 16) | d;
        }
        sOV[m * KPAD + k] = pk;
    }
    __syncthreads();

    // ---- fused epilogue: tropical z + convex/concave + gate blend ----
    // C/D layout col=lane&15, row=quad*4+r  [verified m89/m91]
    #pragma unroll
    for (int mi = 0; mi < 4; mi++) {
        const int mb = wm * 64 + mi * 16 + quad * 4;   // local m of r=0
        int c0 = sCnt[mb], c1 = sCnt[mb + 1], c2 = sCnt[mb + 2], c3 = sCnt[mb + 3];
        int k0c = c0 < KMAX ? c0 : KMAX, k1c = c1 < KMAX ? c1 : KMAX;
        int k2c = c2 < KMAX ? c2 : KMAX, k3c = c3 < KMAX ? c3 : KMAX;
        int km = max(max(k0c, k1c), max(k2c, k3c));
        #pragma unroll
        for (int ni = 0; ni < 2; ni++) {
            const int fl = wn * 32 + ni * 16 + lr;     // local f (obuf col)
            const int f = bf * 128 + fl;
            float z0 = -1e30f, z1 = -1e30f, z2 = -1e30f, z3 = -1e30f;
            for (int k = 0; k < km; k++) {
                int p0 = sOV[(mb + 0) * KPAD + k];
                int p1 = sOV[(mb + 1) * KPAD + k];
                int p2 = sOV[(mb + 2) * KPAD + k];
                int p3 = sOV[(mb + 3) * KPAD + k];
                float w0 = WtT[((p0 & 0xFFFF) << 10) + f];
                float w1 = WtT[((p1 & 0xFFFF) << 10) + f];
                float w2 = WtT[((p2 & 0xFFFF) << 10) + f];
                float w3 = WtT[((p3 & 0xFFFF) << 10) + f];
                z0 = fmaxf(z0, __int_as_float(p0 & 0xFFFF0000) + w0);
                z1 = fmaxf(z1, __int_as_float(p1 & 0xFFFF0000) + w1);
                z2 = fmaxf(z2, __int_as_float(p2 & 0xFFFF0000) + w2);
                z3 = fmaxf(z3, __int_as_float(p3 & 0xFFFF0000) + w3);
            }
            // exact fallback (never expected): full 256-d scan
            if (c0 > KMAX || c1 > KMAX || c2 > KMAX || c3 > KMAX) {
                float zz[4] = { z0, z1, z2, z3 };
                int cc[4] = { c0, c1, c2, c3 };
                #pragma unroll 1
                for (int r = 0; r < 4; r++) if (cc[r] > KMAX) {
                    const float* xr = x + (size_t)(bm * 128 + mb + r) * DM;
                    float m2 = -1e30f;
                    for (int d = 0; d < DM; d++) m2 = fmaxf(m2, xr[d] + WtT[d * NF + f]);
                    zz[r] = m2;
                }
                z0 = zz[0]; z1 = zz[1]; z2 = zz[2]; z3 = zz[3];
            }
            float4 a0 = *(const float4*)(slx + f * 8), a1 = *(const float4*)(slx + f * 8 + 4);
            float4 b0 = *(const float4*)(ofx + f * 8), b1 = *(const float4*)(ofx + f * 8 + 4);
            float4 cc0 = *(const float4*)(slc + f * 8), cc1 = *(const float4*)(slc + f * 8 + 4);
            float4 d0 = *(const float4*)(ofc + f * 8), d1 = *(const float4*)(ofc + f * 8 + 4);
            float btf = bt[f], sf = s[f];
            float bcv = bc[f], bgv = bg[f];
            float zr[4] = { z0, z1, z2, z3 };
            #pragma unroll
            for (int r = 0; r < 4; r++) {
                float z = zr[r] + btf;
                float cvx = fmaf(z, a0.x, b0.x);
                cvx = fmaxf(cvx, fmaf(z, a0.y, b0.y));
                cvx = fmaxf(cvx, fmaf(z, a0.z, b0.z));
                cvx = fmaxf(cvx, fmaf(z, a0.w, b0.w));
                cvx = fmaxf(cvx, fmaf(z, a1.x, b1.x));
                cvx = fmaxf(cvx, fmaf(z, a1.y, b1.y));
                cvx = fmaxf(cvx, fmaf(z, a1.z, b1.z));
                cvx = fmaxf(cvx, fmaf(z, a1.w, b1.w));
                float ccv = fmaf(z, cc0.x, d0.x);
                ccv = fminf(ccv, fmaf(z, cc0.y, d0.y));
                ccv = fminf(ccv, fmaf(z, cc0.z, d0.z));
                ccv = fminf(ccv, fmaf(z, cc0.w, d0.w));
                ccv = fminf(ccv, fmaf(z, cc1.x, d1.x));
                ccv = fminf(ccv, fmaf(z, cc1.y, d1.y));
                ccv = fminf(ccv, fmaf(z, cc1.z, d1.z));
                ccv = fminf(ccv, fmaf(z, cc1.w, d1.w));
                float tv = sf * cvx + (1.0f - sf) * ccv;
                float cpre = accc[mi][ni][r] + bcv;
                float gpre = accg[mi][ni][r] + bgv;
                float g = sigm(gpre);
                float cla = gelu_f(cpre);
                obuf[(wm * 16 + quad * 4 + r) * OSTR + fl] = f2bf(g * tv + (1.0f - g) * cla);
            }
        }
        __syncthreads();   // obuf tile complete
        {   // cooperative coalesced store: 256B contiguous per 16-thread group
            int row = t >> 4, col8 = (t & 15) << 3;
            int gm = bm * 128 + (row >> 4) * 64 + mi * 16 + (row & 15);
            ushort8 v = *(const ushort8*)&obuf[row * OSTR + col8];
            *(ushort8*)&fused[(size_t)gm * NF + bf * 128 + col8] = v;
        }
        __syncthreads();   // obuf reads done before next mi overwrites
    }
}

// ------------------------------------------------- kernel 5: GEMM2 (fused@Wd + bd)
// BK=64: half the barrier count of r5 (16 iters). Grid dim3(2,256): bn fastest.
#define LDS2 64
__global__ __launch_bounds__(512, 4) void gemm2_kernel(
    const unsigned short* __restrict__ A,  // fused [T][1024]
    const unsigned short* __restrict__ Bt, // WdT [256][1024]
    const float* __restrict__ bd, float* __restrict__ out) {
    __shared__ __align__(16) unsigned short As[128 * LDS2];
    __shared__ __align__(16) unsigned short Bs[128 * LDS2];
    const int t = threadIdx.x;
    const int bn = blockIdx.x, bm = blockIdx.y;
    const int wave = t >> 6, lane = t & 63;
    const int wm = wave & 1, wn = wave >> 1;
    const int lr = lane & 15, quad = lane >> 4;
    const int srow = wave * 8 + (lane >> 3), scol = (lane & 7) << 3;  // 64 rows/issue
    const unsigned short* gA = A  + (size_t)(bm * 128 + srow) * NF + scol;
    const unsigned short* gB = Bt + (size_t)(bn * 128 + srow) * NF + scol;
    unsigned short* lA = &As[wave * 8 * LDS2];
    unsigned short* lB = &Bs[wave * 8 * LDS2];

    floatx4 acc[4][2];
    #pragma unroll
    for (int i = 0; i < 4; i++)
        #pragma unroll
        for (int j = 0; j < 2; j++) acc[i][j] = (floatx4)0.0f;

    for (int k0 = 0; k0 < NF; k0 += 64) {
        __syncthreads();
        g2lds16(gA + k0, lA);
        g2lds16(gA + k0 + (size_t)64 * NF, lA + 64 * LDS2);
        g2lds16(gB + k0, lB);
        g2lds16(gB + k0 + (size_t)64 * NF, lB + 64 * LDS2);
        __syncthreads();
        #pragma unroll
        for (int ks = 0; ks < 2; ks++) {
            bf16x8 af[4], bf_[2];
            #pragma unroll
            for (int mi = 0; mi < 4; mi++)
                af[mi] = *(const bf16x8*)&As[(wm * 64 + mi * 16 + lr) * LDS2 + ks * 32 + quad * 8];
            #pragma unroll
            for (int ni = 0; ni < 2; ni++)
                bf_[ni] = *(const bf16x8*)&Bs[(wn * 32 + ni * 16 + lr) * LDS2 + ks * 32 + quad * 8];
            #pragma unroll
            for (int mi = 0; mi < 4; mi++)
                #pragma unroll
                for (int ni = 0; ni < 2; ni++)
                    acc[mi][ni] = __builtin_amdgcn_mfma_f32_16x16x32_bf16(af[mi], bf_[ni], acc[mi][ni], 0, 0, 0);
        }
    }
    #pragma unroll
    for (int mi = 0; mi < 4; mi++)
        #pragma unroll
        for (int ni = 0; ni < 2; ni++) {
            int n = bn * 128 + wn * 32 + ni * 16 + lr;
            float bdv = bd[n];
            #pragma unroll
            for (int r = 0; r < 4; r++) {
                int m = bm * 128 + wm * 64 + mi * 16 + quad * 4 + r;
                out[m * DM + n] = acc[mi][ni][r] + bdv;
            }
        }
}

// ------------------------------------------------------------- launcher
extern "C" void kernel_launch(void* const* d_in, const int* in_sizes, int n_in,
                              void* d_out, int out_size, void* d_ws, size_t ws_size,
                              hipStream_t stream) {
    const float* x     = (const float*)d_in[0];
    const float* Wt    = (const float*)d_in[1];
    const float* bt    = (const float*)d_in[2];
    const float* slx   = (const float*)d_in[3];
    const float* ofx   = (const float*)d_in[4];
    const float* slc   = (const float*)d_in[5];
    const float* ofc   = (const float*)d_in[6];
    const float* alpha = (const float*)d_in[7];
    const float* Wc    = (const float*)d_in[8];
    const float* bc    = (const float*)d_in[9];
    const float* Wg    = (const float*)d_in[10];
    const float* bg    = (const float*)d_in[11];
    const float* Wd    = (const float*)d_in[12];
    const float* bd    = (const float*)d_in[13];
    float* out = (float*)d_out;
    char* ws = (char*)d_ws;

    unsigned int* slot = (unsigned int*)(ws + O_SLOT);
    float* s           = (float*)(ws + O_S);
    unsigned short* Wct = (unsigned short*)(ws + O_WCT);
    unsigned short* Wgt = (unsigned short*)(ws + O_WGT);
    unsigned short* WdT = (unsigned short*)(ws + O_WDT);
    float* WtT          = (float*)(ws + O_WTT);
    unsigned short* xbf = (unsigned short*)(ws + O_XBF);
    int* counts         = (int*)(ws + O_CNT);
    int* cidx           = (int*)(ws + O_CIDX);
    float* cval         = (float*)(ws + O_CVAL);
    unsigned short* fused = (unsigned short*)(ws + O_FUSD);

    pack_kernel<<<1024, 256, 0, stream>>>(Wt, alpha, Wc, Wg, Wd, Wct, Wgt, WdT, WtT, s, slot);
    minmax_kernel<<<128, 256, 0, stream>>>(Wt, slot);
    cand_kernel<<<TTOK, 256, 0, stream>>>(x, slot, xbf, counts, cidx, cval);
    gemm1_kernel<<<dim3(NF / 128, TTOK / 128), 512, 0, stream>>>(
        xbf, Wct, Wgt, bc, bg, counts, cidx, cval, x, WtT, bt,
        slx, ofx, slc, ofc, s, fused);
    gemm2_kernel<<<dim3(DM / 128, TTOK / 128), 512, 0, stream>>>(fused, WdT, bd, out);
}

// Round 7
// 285.392 us; speedup vs baseline: 1.3473x; 1.3473x over previous
//
#include <hip/hip_runtime.h>

// ---------------------------------------------------------------- constants
#define TTOK 32768
#define DM   256
#define NF   1024
#define KMAX 32

typedef __attribute__((ext_vector_type(8))) unsigned short ushort8;
typedef __attribute__((ext_vector_type(8))) __bf16 bf16x8;
typedef __attribute__((ext_vector_type(4))) float floatx4;

// workspace offsets (all 256B aligned)
constexpr size_t O_SLOT = 0;                                   // 1 uint (max|Wt|)
constexpr size_t O_S    = 256;                                 // 1024 f32 sigmoid(alpha)
constexpr size_t O_WCT  = O_S    + 4096;                       // Wc^T  [1024][256] bf16
constexpr size_t O_WGT  = O_WCT  + (size_t)NF*DM*2;            // Wg^T  [1024][256] bf16
constexpr size_t O_WDT  = O_WGT  + (size_t)NF*DM*2;            // Wd^T  [256][1024] bf16
constexpr size_t O_WTT  = O_WDT  + (size_t)DM*NF*2;            // Wt^T  [256][1024] f32
constexpr size_t O_XBF  = O_WTT  + (size_t)DM*NF*4;            // x bf16 [T][256]
constexpr size_t O_CNT  = O_XBF  + (size_t)TTOK*DM*2;          // counts [T]
constexpr size_t O_CIDX = O_CNT  + (size_t)TTOK*4;             // cand d (raw) [T][KMAX]
constexpr size_t O_CVAL = O_CIDX + (size_t)TTOK*KMAX*4;        // cand val [T][KMAX]
constexpr size_t O_FUSD = O_CVAL + (size_t)TTOK*KMAX*4;        // fused bf16 [T][1024]

__device__ __forceinline__ float bf2f(unsigned short u) {
    union { unsigned int i; float f; } c; c.i = ((unsigned int)u) << 16; return c.f;
}
__device__ __forceinline__ unsigned short f2bf(float v) {
    union { float f; unsigned int i; } c; c.f = v;
    unsigned int b = c.i;
    return (unsigned short)((b + 0x7FFFu + ((b >> 16) & 1u)) >> 16);
}
__device__ __forceinline__ float sigm(float z) { return 1.0f / (1.0f + __expf(-z)); }
// tanh-gelu: max |diff| vs exact erf-gelu ~3e-3, far under 0.266 tolerance
__device__ __forceinline__ float gelu_f(float x) {
    return x * sigm(1.59576912f * (x + 0.044715f * x * x * x));
}
// async global->LDS, 16B per lane; lds dest = wave-uniform base + lane*16 [m97/m104]
__device__ __forceinline__ void g2lds16(const unsigned short* g, unsigned short* l) {
    __builtin_amdgcn_global_load_lds((const __attribute__((address_space(1))) unsigned int*)g,
                                     (__attribute__((address_space(3))) unsigned int*)l, 16, 0, 0);
}

// ------------------------------------------------- kernel 1: pack weights
__global__ void pack_kernel(const float* __restrict__ Wt, const float* __restrict__ alpha,
                            const float* __restrict__ Wc, const float* __restrict__ Wg,
                            const float* __restrict__ Wd,
                            unsigned short* __restrict__ Wct, unsigned short* __restrict__ Wgt,
                            unsigned short* __restrict__ WdT, float* __restrict__ WtT,
                            float* __restrict__ s, unsigned int* __restrict__ slot) {
    int e = blockIdx.x * 256 + threadIdx.x;
    if (e == 0) *slot = 0u;
    { int f = e >> 8, k = e & 255;           // Wc/Wg are [256][1024]
      Wct[e] = f2bf(Wc[k * NF + f]);
      Wgt[e] = f2bf(Wg[k * NF + f]); }
    { int n = e >> 10, k = e & 1023;         // Wd is [1024][256]
      WdT[e] = f2bf(Wd[k * DM + n]); }
    { int d = e >> 10, f = e & 1023;         // Wt is [1024][256]
      WtT[e] = Wt[f * DM + d]; }
    if (e < NF) s[e] = sigm(alpha[e]);
}

// ------------------------------------------------- kernel 2: max|Wt| reduce
__global__ void minmax_kernel(const float* __restrict__ Wt, unsigned int* __restrict__ slot) {
    int g = blockIdx.x * 256 + threadIdx.x;
    float lm = 0.0f;
    for (int i = g; i < NF * DM; i += 128 * 256) lm = fmaxf(lm, fabsf(Wt[i]));
    #pragma unroll
    for (int o = 32; o > 0; o >>= 1) lm = fmaxf(lm, __shfl_xor(lm, o));
    if ((threadIdx.x & 63) == 0) atomicMax(slot, __float_as_uint(lm)); // |w|>=0: uint order ok
}

// ------------------------------------------------- kernel 3: candidates + x->bf16
__global__ void cand_kernel(const float* __restrict__ x, const unsigned int* __restrict__ slot,
                            unsigned short* __restrict__ xbf, int* __restrict__ counts,
                            int* __restrict__ cidx, float* __restrict__ cval) {
    int i = blockIdx.x, t = threadIdx.x;
    float v = x[i * DM + t];
    xbf[i * DM + t] = f2bf(v);
    float m = v;
    #pragma unroll
    for (int o = 32; o > 0; o >>= 1) m = fmaxf(m, __shfl_xor(m, o));
    __shared__ float wm[4];
    __shared__ int cnt;
    __shared__ int sidx[KMAX];
    __shared__ float sval[KMAX];
    if ((t & 63) == 0) wm[t >> 6] = m;
    if (t == 0) cnt = 0;
    __syncthreads();
    float xmax = fmaxf(fmaxf(wm[0], wm[1]), fmaxf(wm[2], wm[3]));
    float delta = 2.0f * __uint_as_float(*slot);   // >= Wmax - Wmin : exact exclusion bound
    float thr = xmax - delta;
    if (v >= thr) {
        int p = atomicAdd(&cnt, 1);
        if (p < KMAX) { sidx[p] = t; sval[p] = v; }   // raw d index
    }
    __syncthreads();
    int c = cnt;
    if (t == 0) counts[i] = c;
    if (t < (c < KMAX ? c : KMAX)) {
        cidx[i * KMAX + t] = sidx[t];
        cval[i * KMAX + t] = sval[t];
    }
}

// ------------------------------------------------- kernel 4: fused GEMM1
// (x@Wc, x@Wg) MFMA + tropical max-plus + convex/concave + gate blend.
// 128x128 tile, BK=32, 512 thr (8 waves 2Mx4F, wave 64x32 dual-output).
// r6 lessons fixed here:
//  - XCD swizzle: b&7 selects XCD (dispatch round-robin); make the 8
//    bf-siblings of a bm CONSECUTIVE within one XCD's stream -> A-tile+meta
//    L2-hot (r6's bf-fastest put siblings on 8 different L2s: FETCH 168MB).
//  - Epilogue params (36 f32/f) staged in LDS, not VGPRs: r5/r6 spilled
//    (WRITE 192512KB bit-constant = scratch), since params+z+acc > 128 regs.
//  - Full-tile obuf (OSTR=136: <=2-way banks), ONE cooperative 32KB store.
//  - Gather breadth 8 (both ni interleaved) to cover L2 latency.
#define LDSS 32   // ushorts per LDS row, no pad (wave-uniform-base DMA, m104)
#define KPAD 33
#define OSTR 136  // obuf row stride in ushorts (272B, 16q+4r+col bank spread)
__global__ __launch_bounds__(512, 4) void gemm1_kernel(
    const unsigned short* __restrict__ A,   // xbf [T][256]
    const unsigned short* __restrict__ Bct, // [1024][256]
    const unsigned short* __restrict__ Bgt, // [1024][256]
    const float* __restrict__ bc, const float* __restrict__ bg,
    const int* __restrict__ counts, const int* __restrict__ cidx,
    const float* __restrict__ cval, const float* __restrict__ x,
    const float* __restrict__ WtT, const float* __restrict__ bt,
    const float* __restrict__ slx, const float* __restrict__ ofx,
    const float* __restrict__ slc, const float* __restrict__ ofc,
    const float* __restrict__ s, unsigned short* __restrict__ fused) {
    __shared__ __align__(16) char smem[76800];
    unsigned short* As  = (unsigned short*)smem;            // [0, 8K)     K-loop
    unsigned short* Bcs = As + 4096;                        // [8K, 16K)   K-loop
    unsigned short* Bgs = As + 8192;                        // [16K, 24K)  K-loop
    float* par = (float*)smem;                              // [0, 18K)    epilogue (overlay)
    int* sOV  = (int*)(smem + 24576);                       // [24K, 40.5K)
    int* sCnt = (int*)(smem + 41472);                       // 512B
    unsigned short* obuf = (unsigned short*)(smem + 41984); // 34816B
    const int t = threadIdx.x;
    // XCD-aware swizzle (speed heuristic only; correctness order-free)
    const int b = blockIdx.x;
    const int xcd = b & 7, j = b >> 3;
    const int bf = j & 7;
    const int bm = (j >> 3) * 8 + xcd;
    const int wave = t >> 6, lane = t & 63;
    const int wm = wave & 1, wn = wave >> 1;
    const int lr = lane & 15, quad = lane >> 4;
    const int srow = wave * 16 + (lane >> 2), scol = (lane & 3) << 3;
    const unsigned short* gA = A   + (size_t)(bm * 128 + srow) * DM + scol;
    const unsigned short* gC = Bct + (size_t)(bf * 128 + srow) * DM + scol;
    const unsigned short* gG = Bgt + (size_t)(bf * 128 + srow) * DM + scol;
    unsigned short* lA = &As[wave * 16 * LDSS];
    unsigned short* lC = &Bcs[wave * 16 * LDSS];
    unsigned short* lG = &Bgs[wave * 16 * LDSS];

    if (t < 128) sCnt[t] = counts[bm * 128 + t];

    floatx4 accc[4][2], accg[4][2];
    #pragma unroll
    for (int i = 0; i < 4; i++)
        #pragma unroll
        for (int jj = 0; jj < 2; jj++) { accc[i][jj] = (floatx4)0.0f; accg[i][jj] = (floatx4)0.0f; }

    for (int k0 = 0; k0 < DM; k0 += 32) {
        __syncthreads();            // covers sCnt stage (1st iter) + prior ds_reads
        g2lds16(gA + k0, lA);
        g2lds16(gC + k0, lC);
        g2lds16(gG + k0, lG);
        __syncthreads();
        bf16x8 af[4], bcf[2], bgf[2];
        #pragma unroll
        for (int mi = 0; mi < 4; mi++)
            af[mi] = *(const bf16x8*)&As[(wm * 64 + mi * 16 + lr) * LDSS + quad * 8];
        #pragma unroll
        for (int ni = 0; ni < 2; ni++) {
            bcf[ni] = *(const bf16x8*)&Bcs[(wn * 32 + ni * 16 + lr) * LDSS + quad * 8];
            bgf[ni] = *(const bf16x8*)&Bgs[(wn * 32 + ni * 16 + lr) * LDSS + quad * 8];
        }
        #pragma unroll
        for (int mi = 0; mi < 4; mi++)
            #pragma unroll
            for (int ni = 0; ni < 2; ni++) {
                accc[mi][ni] = __builtin_amdgcn_mfma_f32_16x16x32_bf16(af[mi], bcf[ni], accc[mi][ni], 0, 0, 0);
                accg[mi][ni] = __builtin_amdgcn_mfma_f32_16x16x32_bf16(af[mi], bgf[ni], accg[mi][ni], 0, 0, 0);
            }
    }
    __syncthreads();   // staging bufs dead; overlay par

    // ---- stage epilogue params into LDS: par[fl*36 + {0..7 slx, 8..15 ofx,
    //      16..23 slc, 24..31 ofc, 32 bt, 33 s, 34 bc, 35 bg}]
    for (int e = t; e < 1024; e += 512) {
        int ff = e >> 3, w = e & 7;
        int gf = (bf * 128 + ff) * 8 + w;
        par[ff * 36 + w]      = slx[gf];
        par[ff * 36 + 8 + w]  = ofx[gf];
        par[ff * 36 + 16 + w] = slc[gf];
        par[ff * 36 + 24 + w] = ofc[gf];
    }
    if (t < 128) {
        int gf = bf * 128 + t;
        par[t * 36 + 32] = bt[gf];
        par[t * 36 + 33] = s[gf];
        par[t * 36 + 34] = bc[gf];
        par[t * 36 + 35] = bg[gf];
    }
    // ---- stage packed candidate meta (pre-padded: d=0, val=-1e30 -> branchless)
    const int PADV = (int)(((unsigned int)f2bf(-1e30f)) << 16);
    for (int e = t; e < 128 * KMAX; e += 512) {
        int m = e >> 5, k = e & 31;
        int c = sCnt[m];
        int pk = PADV;
        if (k < (c < KMAX ? c : KMAX)) {
            int d  = cidx[(size_t)(bm * 128 + m) * KMAX + k];
            float v = cval[(size_t)(bm * 128 + m) * KMAX + k];
            pk = (int)(((unsigned int)f2bf(v)) << 16) | d;
        }
        sOV[m * KPAD + k] = pk;
    }
    __syncthreads();

    // ---- fused epilogue: tropical z + convex/concave + gate blend ----
    // C/D layout col=lane&15, row=quad*4+r  [verified m89/m91]
    const int f0 = bf * 128 + wn * 32 + lr;    // ni=0 global f; ni=1 is +16
    #pragma unroll
    for (int mi = 0; mi < 4; mi++) {
        const int mb = wm * 64 + mi * 16 + quad * 4;   // local m of r=0
        int c0 = sCnt[mb], c1 = sCnt[mb + 1], c2 = sCnt[mb + 2], c3 = sCnt[mb + 3];
        int k0c = c0 < KMAX ? c0 : KMAX, k1c = c1 < KMAX ? c1 : KMAX;
        int k2c = c2 < KMAX ? c2 : KMAX, k3c = c3 < KMAX ? c3 : KMAX;
        int km = max(max(k0c, k1c), max(k2c, k3c));
        float z0a = -1e30f, z1a = -1e30f, z2a = -1e30f, z3a = -1e30f;  // ni=0
        float z0b = -1e30f, z1b = -1e30f, z2b = -1e30f, z3b = -1e30f;  // ni=1
        for (int k = 0; k < km; k++) {
            int p0 = sOV[(mb + 0) * KPAD + k];
            int p1 = sOV[(mb + 1) * KPAD + k];
            int p2 = sOV[(mb + 2) * KPAD + k];
            int p3 = sOV[(mb + 3) * KPAD + k];
            const float* r0 = WtT + ((p0 & 0xFFFF) << 10) + f0;
            const float* r1 = WtT + ((p1 & 0xFFFF) << 10) + f0;
            const float* r2 = WtT + ((p2 & 0xFFFF) << 10) + f0;
            const float* r3 = WtT + ((p3 & 0xFFFF) << 10) + f0;
            float w0a = r0[0], w0b = r0[16];
            float w1a = r1[0], w1b = r1[16];
            float w2a = r2[0], w2b = r2[16];
            float w3a = r3[0], w3b = r3[16];
            float v0 = __int_as_float(p0 & 0xFFFF0000);
            float v1 = __int_as_float(p1 & 0xFFFF0000);
            float v2 = __int_as_float(p2 & 0xFFFF0000);
            float v3 = __int_as_float(p3 & 0xFFFF0000);
            z0a = fmaxf(z0a, v0 + w0a); z0b = fmaxf(z0b, v0 + w0b);
            z1a = fmaxf(z1a, v1 + w1a); z1b = fmaxf(z1b, v1 + w1b);
            z2a = fmaxf(z2a, v2 + w2a); z2b = fmaxf(z2b, v2 + w2b);
            z3a = fmaxf(z3a, v3 + w3a); z3b = fmaxf(z3b, v3 + w3b);
        }
        // exact fallback (never expected): full 256-d scan
        if (c0 > KMAX || c1 > KMAX || c2 > KMAX || c3 > KMAX) {
            float za[4] = { z0a, z1a, z2a, z3a };
            float zb[4] = { z0b, z1b, z2b, z3b };
            int cc[4] = { c0, c1, c2, c3 };
            #pragma unroll 1
            for (int r = 0; r < 4; r++) if (cc[r] > KMAX) {
                const float* xr = x + (size_t)(bm * 128 + mb + r) * DM;
                float ma = -1e30f, mbv = -1e30f;
                for (int d = 0; d < DM; d++) {
                    float xv = xr[d];
                    ma  = fmaxf(ma,  xv + WtT[d * NF + f0]);
                    mbv = fmaxf(mbv, xv + WtT[d * NF + f0 + 16]);
                }
                za[r] = ma; zb[r] = mbv;
            }
            z0a = za[0]; z1a = za[1]; z2a = za[2]; z3a = za[3];
            z0b = zb[0]; z1b = zb[1]; z2b = zb[2]; z3b = zb[3];
        }
        #pragma unroll
        for (int ni = 0; ni < 2; ni++) {
            const int fl = wn * 32 + ni * 16 + lr;
            const float* pp = par + fl * 36;
            float4 a0 = *(const float4*)(pp),      a1 = *(const float4*)(pp + 4);
            float4 b0 = *(const float4*)(pp + 8),  b1 = *(const float4*)(pp + 12);
            float4 cc0 = *(const float4*)(pp + 16), cc1 = *(const float4*)(pp + 20);
            float4 d0 = *(const float4*)(pp + 24), d1 = *(const float4*)(pp + 28);
            float4 sc = *(const float4*)(pp + 32);  // bt, s, bc, bg
            float zr[4];
            if (ni == 0) { zr[0] = z0a; zr[1] = z1a; zr[2] = z2a; zr[3] = z3a; }
            else         { zr[0] = z0b; zr[1] = z1b; zr[2] = z2b; zr[3] = z3b; }
            #pragma unroll
            for (int r = 0; r < 4; r++) {
                float z = zr[r] + sc.x;
                float cvx = fmaf(z, a0.x, b0.x);
                cvx = fmaxf(cvx, fmaf(z, a0.y, b0.y));
                cvx = fmaxf(cvx, fmaf(z, a0.z, b0.z));
                cvx = fmaxf(cvx, fmaf(z, a0.w, b0.w));
                cvx = fmaxf(cvx, fmaf(z, a1.x, b1.x));
                cvx = fmaxf(cvx, fmaf(z, a1.y, b1.y));
                cvx = fmaxf(cvx, fmaf(z, a1.z, b1.z));
                cvx = fmaxf(cvx, fmaf(z, a1.w, b1.w));
                float ccv = fmaf(z, cc0.x, d0.x);
                ccv = fminf(ccv, fmaf(z, cc0.y, d0.y));
                ccv = fminf(ccv, fmaf(z, cc0.z, d0.z));
                ccv = fminf(ccv, fmaf(z, cc0.w, d0.w));
                ccv = fminf(ccv, fmaf(z, cc1.x, d1.x));
                ccv = fminf(ccv, fmaf(z, cc1.y, d1.y));
                ccv = fminf(ccv, fmaf(z, cc1.z, d1.z));
                ccv = fminf(ccv, fmaf(z, cc1.w, d1.w));
                float tv = sc.y * cvx + (1.0f - sc.y) * ccv;
                float cpre = accc[mi][ni][r] + sc.z;
                float gpre = accg[mi][ni][r] + sc.w;
                float g = sigm(gpre);
                float cla = gelu_f(cpre);
                obuf[(mb + r) * OSTR + fl] = f2bf(g * tv + (1.0f - g) * cla);
            }
        }
    }
    __syncthreads();   // full 128x128 obuf tile complete
    // cooperative coalesced store: 256B contiguous per row-segment
    #pragma unroll
    for (int e = t; e < 128 * 16; e += 512) {
        int row = e >> 4, c8 = (e & 15) << 3;
        ushort8 v = *(const ushort8*)&obuf[row * OSTR + c8];
        *(ushort8*)&fused[(size_t)(bm * 128 + row) * NF + bf * 128 + c8] = v;
    }
}

// ------------------------------------------------- kernel 5: GEMM2 (fused@Wd + bd)
// BK=64, 16 K-iters. XCD swizzle: the 2 bn-siblings of a bm consecutive per XCD.
#define LDS2 64
__global__ __launch_bounds__(512, 4) void gemm2_kernel(
    const unsigned short* __restrict__ A,  // fused [T][1024]
    const unsigned short* __restrict__ Bt, // WdT [256][1024]
    const float* __restrict__ bd, float* __restrict__ out) {
    __shared__ __align__(16) unsigned short As[128 * LDS2];
    __shared__ __align__(16) unsigned short Bs[128 * LDS2];
    const int t = threadIdx.x;
    const int b = blockIdx.x;
    const int xcd = b & 7, j = b >> 3;
    const int bn = j & 1;
    const int bm = (j >> 1) * 8 + xcd;
    const int wave = t >> 6, lane = t & 63;
    const int wm = wave & 1, wn = wave >> 1;
    const int lr = lane & 15, quad = lane >> 4;
    const int srow = wave * 8 + (lane >> 3), scol = (lane & 7) << 3;  // 64 rows/issue
    const unsigned short* gA = A  + (size_t)(bm * 128 + srow) * NF + scol;
    const unsigned short* gB = Bt + (size_t)(bn * 128 + srow) * NF + scol;
    unsigned short* lA = &As[wave * 8 * LDS2];
    unsigned short* lB = &Bs[wave * 8 * LDS2];

    floatx4 acc[4][2];
    #pragma unroll
    for (int i = 0; i < 4; i++)
        #pragma unroll
        for (int jj = 0; jj < 2; jj++) acc[i][jj] = (floatx4)0.0f;

    for (int k0 = 0; k0 < NF; k0 += 64) {
        __syncthreads();
        g2lds16(gA + k0, lA);
        g2lds16(gA + k0 + (size_t)64 * NF, lA + 64 * LDS2);
        g2lds16(gB + k0, lB);
        g2lds16(gB + k0 + (size_t)64 * NF, lB + 64 * LDS2);
        __syncthreads();
        #pragma unroll
        for (int ks = 0; ks < 2; ks++) {
            bf16x8 af[4], bf_[2];
            #pragma unroll
            for (int mi = 0; mi < 4; mi++)
                af[mi] = *(const bf16x8*)&As[(wm * 64 + mi * 16 + lr) * LDS2 + ks * 32 + quad * 8];
            #pragma unroll
            for (int ni = 0; ni < 2; ni++)
                bf_[ni] = *(const bf16x8*)&Bs[(wn * 32 + ni * 16 + lr) * LDS2 + ks * 32 + quad * 8];
            #pragma unroll
            for (int mi = 0; mi < 4; mi++)
                #pragma unroll
                for (int ni = 0; ni < 2; ni++)
                    acc[mi][ni] = __builtin_amdgcn_mfma_f32_16x16x32_bf16(af[mi], bf_[ni], acc[mi][ni], 0, 0, 0);
        }
    }
    #pragma unroll
    for (int mi = 0; mi < 4; mi++)
        #pragma unroll
        for (int ni = 0; ni < 2; ni++) {
            int n = bn * 128 + wn * 32 + ni * 16 + lr;
            float bdv = bd[n];
            #pragma unroll
            for (int r = 0; r < 4; r++) {
                int m = bm * 128 + wm * 64 + mi * 16 + quad * 4 + r;
                out[m * DM + n] = acc[mi][ni][r] + bdv;
            }
        }
}

// ------------------------------------------------------------- launcher
extern "C" void kernel_launch(void* const* d_in, const int* in_sizes, int n_in,
                              void* d_out, int out_size, void* d_ws, size_t ws_size,
                              hipStream_t stream) {
    const float* x     = (const float*)d_in[0];
    const float* Wt    = (const float*)d_in[1];
    const float* bt    = (const float*)d_in[2];
    const float* slx   = (const float*)d_in[3];
    const float* ofx   = (const float*)d_in[4];
    const float* slc   = (const float*)d_in[5];
    const float* ofc   = (const float*)d_in[6];
    const float* alpha = (const float*)d_in[7];
    const float* Wc    = (const float*)d_in[8];
    const float* bc    = (const float*)d_in[9];
    const float* Wg    = (const float*)d_in[10];
    const float* bg    = (const float*)d_in[11];
    const float* Wd    = (const float*)d_in[12];
    const float* bd    = (const float*)d_in[13];
    float* out = (float*)d_out;
    char* ws = (char*)d_ws;

    unsigned int* slot = (unsigned int*)(ws + O_SLOT);
    float* s           = (float*)(ws + O_S);
    unsigned short* Wct = (unsigned short*)(ws + O_WCT);
    unsigned short* Wgt = (unsigned short*)(ws + O_WGT);
    unsigned short* WdT = (unsigned short*)(ws + O_WDT);
    float* WtT          = (float*)(ws + O_WTT);
    unsigned short* xbf = (unsigned short*)(ws + O_XBF);
    int* counts         = (int*)(ws + O_CNT);
    int* cidx           = (int*)(ws + O_CIDX);
    float* cval         = (float*)(ws + O_CVAL);
    unsigned short* fused = (unsigned short*)(ws + O_FUSD);

    pack_kernel<<<1024, 256, 0, stream>>>(Wt, alpha, Wc, Wg, Wd, Wct, Wgt, WdT, WtT, s, slot);
    minmax_kernel<<<128, 256, 0, stream>>>(Wt, slot);
    cand_kernel<<<TTOK, 256, 0, stream>>>(x, slot, xbf, counts, cidx, cval);
    gemm1_kernel<<<2048, 512, 0, stream>>>(
        xbf, Wct, Wgt, bc, bg, counts, cidx, cval, x, WtT, bt,
        slx, ofx, slc, ofc, s, fused);
    gemm2_kernel<<<512, 512, 0, stream>>>(fused, WdT, bd, out);
}